// Round 8
// baseline (1415.801 us; speedup 1.0000x reference)
//
#include <hip/hip_runtime.h>
#include <hip/hip_bf16.h>

#define B_SZ 2
#define H_SZ 16
#define S_SZ 2048
#define D_SZ 64
#define WAVES 8
#define NBH  (B_SZ * H_SZ)      // 32
#define NQB  (S_SZ / 16)        // 128 16-row K blocks per bh
#define NUB  (S_SZ / 32)        // 64 32-row V blocks per bh

typedef __bf16 bf16x8 __attribute__((ext_vector_type(8)));
typedef float  f32x4  __attribute__((ext_vector_type(4)));

// d_ws layout: pre-swizzled bf16 MFMA fragments (8 MB segments)
#define SEG   (8u * 1024u * 1024u)
#define KHI_OFF (0 * (size_t)SEG)
#define KLO_OFF (1 * (size_t)SEG)
#define VSW_OFF (2 * (size_t)SEG)

// ---- prep K: fp32 -> bf16 hi/lo, swizzled to MFMA A-fragment order.
__global__ __launch_bounds__(256) void prep_k(
    const float* __restrict__ K, char* __restrict__ ws)
{
    const int lane = threadIdx.x & 63;
    const int wv   = threadIdx.x >> 6;
    const int l15  = lane & 15;
    const int g    = lane >> 4;
    const int wid  = blockIdx.x * 4 + wv;          // 0..4095
    const int bh   = wid >> 7;
    const int blk  = wid & 127;

    const float* src = K + ((size_t)bh * S_SZ + blk * 16 + l15) * D_SZ;
    bf16x8* hi = (bf16x8*)(ws + KHI_OFF);
    bf16x8* lo = (bf16x8*)(ws + KLO_OFF);

    #pragma unroll
    for (int ks = 0; ks < 2; ++ks) {
        const float* p = src + 32 * ks + 8 * g;
        f32x4 a = *(const f32x4*)p;
        f32x4 b = *(const f32x4*)(p + 4);
        bf16x8 vh, vl;
        #pragma unroll
        for (int j = 0; j < 4; ++j) {
            __bf16 h0 = (__bf16)a[j];
            __bf16 h1 = (__bf16)b[j];
            vh[j]     = h0;
            vh[4 + j] = h1;
            vl[j]     = (__bf16)(a[j] - (float)h0);
            vl[4 + j] = (__bf16)(b[j] - (float)h1);
        }
        size_t di = ((size_t)(bh * NQB + blk) * 2 + ks) * 64 + lane;
        hi[di] = vh;
        lo[di] = vl;
    }
}

// ---- prep V: fp32 -> bf16, B-fragment order with pi-permutation baked in.
__global__ __launch_bounds__(256) void prep_v(
    const float* __restrict__ V, char* __restrict__ ws)
{
    __shared__ float vt[4][32 * 68];
    const int lane = threadIdx.x & 63;
    const int wv   = threadIdx.x >> 6;
    const int l15  = lane & 15;
    const int g    = lane >> 4;
    const int wid  = blockIdx.x * 4 + wv;          // 0..2047
    const int bh   = wid >> 6;
    const int u    = wid & 63;

    const float* src = V + ((size_t)bh * S_SZ + u * 32) * D_SZ;
    float* t = vt[wv];
    #pragma unroll
    for (int i = 0; i < 8; ++i) {
        int idx = i * 64 + lane;
        int row = idx >> 4;
        int c4  = idx & 15;
        *(f32x4*)(t + row * 68 + c4 * 4) = *(const f32x4*)(src + row * 64 + c4 * 4);
    }
    __syncthreads();

    bf16x8* vsw = (bf16x8*)(ws + VSW_OFF);
    #pragma unroll
    for (int db = 0; db < 4; ++db) {
        bf16x8 vb;
        #pragma unroll
        for (int j = 0; j < 8; ++j) {
            int kk = (j < 4) ? (4 * g + j) : (16 + 4 * g + (j - 4));
            vb[j] = (__bf16)t[kk * 68 + 16 * db + l15];
        }
        vsw[((size_t)(bh * NUB + u) * 4 + db) * 64 + lane] = vb;
    }
}

// ---- main fused kernel: 512 threads / 8 waves, TWO 16-row q-tiles per wg,
// processed sequentially. Each tile's W NT-stores are issued after the
// tile's LAST barrier (W swept LDS->regs first, ctxred reuses W-LDS), so
// the 131 KB store slab drains during the NEXT tile's QK^T read phase --
// structural read/write overlap without extra LDS.
__global__ __launch_bounds__(512, 4) void attn_fused6(
    const float* __restrict__ Q, const char* __restrict__ ws,
    float* __restrict__ OutC, float* __restrict__ OutW)
{
    __shared__ __align__(16) char smem[66560];   // 64KB W-tile + redm + reds
    float* redm = (float*)(smem + 65536);        // [8][16]
    float* reds = (float*)(smem + 65536 + 512);  // [8][16]

    const int tid  = threadIdx.x;
    const int lane = tid & 63;
    const int wv   = tid >> 6;
    const int l15  = lane & 15;
    const int g    = lane >> 4;

    // XCD-aware swizzle: 2048 wgs; XCD x owns a contiguous 256-wg chunk
    const int b    = blockIdx.x;
    const int work = (b & 7) * 256 + (b >> 3);
    const int bh   = work >> 6;
    const int qt   = work & 63;          // 32-row group index
    const int q0   = qt * 32;

    const bf16x8* KHI = (const bf16x8*)(ws + KHI_OFF);
    const bf16x8* KLO = (const bf16x8*)(ws + KLO_OFF);
    const bf16x8* VSW = (const bf16x8*)(ws + VSW_OFF);

    float* Wb = OutW + (size_t)bh * S_SZ * S_SZ;
    float* Cb = OutC + (size_t)bh * S_SZ * D_SZ;

    for (int t = 0; t < 2; ++t) {
        const int r0 = q0 + 16 * t;

        // ---- Q fragments: direct fp32 load + hi/lo split (4 KB per tile)
        bf16x8 qhi[2], qlo[2];
        {
            const float* qp = Q + ((size_t)bh * S_SZ + r0 + l15) * D_SZ + 8 * g;
            #pragma unroll
            for (int ks = 0; ks < 2; ++ks) {
                f32x4 a  = *(const f32x4*)(qp + 32 * ks);
                f32x4 b2 = *(const f32x4*)(qp + 32 * ks + 4);
                #pragma unroll
                for (int j = 0; j < 4; ++j) {
                    __bf16 h0 = (__bf16)a[j];
                    __bf16 h1 = (__bf16)b2[j];
                    qhi[ks][j]     = h0;
                    qhi[ks][4 + j] = h1;
                    qlo[ks][j]     = (__bf16)(a[j]  - (float)h0);
                    qlo[ks][4 + j] = (__bf16)(b2[j] - (float)h1);
                }
            }
        }

        // ---- QK^T: 16 col-blocks per wave, 6 MFMA each (3-term bf16 split)
        // (tile t==1: these K reads overlap tile 0's W-store drain)
        f32x4 s[16];
        #pragma unroll
        for (int cb = 0; cb < 16; ++cb) {
            size_t bi = ((size_t)(bh * NQB + wv * 16 + cb) * 2) * 64 + lane;
            bf16x8 kh0 = KHI[bi], kh1 = KHI[bi + 64];
            bf16x8 kl0 = KLO[bi], kl1 = KLO[bi + 64];
            f32x4 acc = {0.f, 0.f, 0.f, 0.f};
            acc = __builtin_amdgcn_mfma_f32_16x16x32_bf16(kh0, qhi[0], acc, 0, 0, 0);
            acc = __builtin_amdgcn_mfma_f32_16x16x32_bf16(kh0, qlo[0], acc, 0, 0, 0);
            acc = __builtin_amdgcn_mfma_f32_16x16x32_bf16(kl0, qhi[0], acc, 0, 0, 0);
            acc = __builtin_amdgcn_mfma_f32_16x16x32_bf16(kh1, qhi[1], acc, 0, 0, 0);
            acc = __builtin_amdgcn_mfma_f32_16x16x32_bf16(kh1, qlo[1], acc, 0, 0, 0);
            acc = __builtin_amdgcn_mfma_f32_16x16x32_bf16(kl1, qhi[1], acc, 0, 0, 0);
            s[cb] = acc;
        }

        // ---- row max
        float m = -3.0e38f;
        #pragma unroll
        for (int cb = 0; cb < 16; ++cb) {
            #pragma unroll
            for (int r = 0; r < 4; ++r) m = fmaxf(m, s[cb][r]);
        }
        m = fmaxf(m, __shfl_xor(m, 16));
        m = fmaxf(m, __shfl_xor(m, 32));
        if (lane < 16) redm[wv * 16 + l15] = m;
        __syncthreads();                 // (tile 1: also orders ctxred(A) vs stage(B))
        float mall = redm[l15];
        #pragma unroll
        for (int w2 = 1; w2 < WAVES; ++w2) mall = fmaxf(mall, redm[w2 * 16 + l15]);

        // ---- exp + row sum
        float sm = 0.f;
        #pragma unroll
        for (int cb = 0; cb < 16; ++cb) {
            #pragma unroll
            for (int r = 0; r < 4; ++r) {
                float e = __expf(s[cb][r] - mall);
                s[cb][r] = e;
                sm += e;
            }
        }
        sm += __shfl_xor(sm, 16);
        sm += __shfl_xor(sm, 32);
        if (lane < 16) reds[wv * 16 + l15] = sm;
        __syncthreads();
        float lsum = 0.f;
        #pragma unroll
        for (int w2 = 0; w2 < WAVES; ++w2) lsum += reds[w2 * 16 + l15];
        const float inv = 1.0f / lsum;

        // ---- normalize -> pack P bf16 -> stage W tile in LDS (frees s[])
        // 16B-granule XOR swizzle: byte = row*4096 + ((c4*8) ^ ((row&7)<<4))
        bf16x8 pa[8];
        const int swz = (l15 & 7) << 4;
        #pragma unroll
        for (int u = 0; u < 8; ++u) {
            f32x4 w0, w1;
            #pragma unroll
            for (int r = 0; r < 4; ++r) {
                w0[r] = s[2 * u][r]     * inv;
                w1[r] = s[2 * u + 1][r] * inv;
            }
            #pragma unroll
            for (int r = 0; r < 4; ++r) {
                pa[u][r]     = (__bf16)w0[r];
                pa[u][4 + r] = (__bf16)w1[r];
            }
            const uint2* pau = (const uint2*)&pa[u];
            int c4a = wv * 64 + (2 * u) * 4 + g;
            int c4b = c4a + 4;
            *(uint2*)(smem + l15 * 4096 + ((c4a * 8) ^ swz)) = pau[0];
            *(uint2*)(smem + l15 * 4096 + ((c4b * 8) ^ swz)) = pau[1];
        }
        __syncthreads();

        // ---- PV: A = packed P, B = pre-permuted V fragments
        f32x4 ctx[4];
        #pragma unroll
        for (int db = 0; db < 4; ++db) ctx[db] = (f32x4){0.f, 0.f, 0.f, 0.f};
        #pragma unroll
        for (int u = 0; u < 8; ++u) {
            size_t vbase = ((size_t)(bh * NUB + wv * 8 + u) * 4) * 64 + lane;
            #pragma unroll
            for (int db = 0; db < 4; ++db) {
                bf16x8 vb = VSW[vbase + (size_t)db * 64];
                ctx[db] = __builtin_amdgcn_mfma_f32_16x16x32_bf16(pa[u], vb, ctx[db], 0, 0, 0);
            }
        }

        // ---- sweep W tile LDS -> registers (8 x uint4 per thread)
        uint4 wreg[8];
        #pragma unroll
        for (int sidx = 0; sidx < 8; ++sidx) {
            int unit = sidx * 512 + tid;        // 16B units; 256 per row
            int row  = unit >> 8;
            int c16  = unit & 255;
            wreg[sidx] = *(const uint4*)(smem + row * 4096 + ((c16 * 16) ^ ((row & 7) << 4)));
        }
        __syncthreads();    // LDS reads done; W-LDS free; no vmem stores pending

        // ---- ctx reduction reusing W-LDS
        float* ctxred = (float*)smem;    // [8][16][64] = 32 KB
        #pragma unroll
        for (int db = 0; db < 4; ++db) {
            #pragma unroll
            for (int r = 0; r < 4; ++r)
                ctxred[(wv * 16 + 4 * g + r) * 64 + 16 * db + l15] = ctx[db][r];
        }
        __syncthreads();
        {
            const int qr = tid >> 6;
            const int d  = tid & 63;
            float acc0 = 0.f, acc1 = 0.f;
            #pragma unroll
            for (int w2 = 0; w2 < WAVES; ++w2) {
                acc0 += ctxred[(w2 * 16 + qr) * 64 + d];
                acc1 += ctxred[(w2 * 16 + qr + 8) * 64 + d];
            }
            __builtin_nontemporal_store(acc0, Cb + (size_t)(r0 + qr) * D_SZ + d);
            __builtin_nontemporal_store(acc1, Cb + (size_t)(r0 + qr + 8) * D_SZ + d);
        }

        // ---- issue W NT stores from registers -- AFTER the tile's last
        // barrier, so they drain under the next tile's QK^T (or kernel tail).
        {
            float* Wrow = Wb + (size_t)r0 * S_SZ;
            #pragma unroll
            for (int sidx = 0; sidx < 8; ++sidx) {
                int unit = sidx * 512 + tid;
                int row  = unit >> 8;
                int c16  = unit & 255;
                uint4 u4 = wreg[sidx];
                f32x4 f0, f1;
                f0[0] = __uint_as_float(u4.x << 16);
                f0[1] = __uint_as_float(u4.x & 0xffff0000u);
                f0[2] = __uint_as_float(u4.y << 16);
                f0[3] = __uint_as_float(u4.y & 0xffff0000u);
                f1[0] = __uint_as_float(u4.z << 16);
                f1[1] = __uint_as_float(u4.z & 0xffff0000u);
                f1[2] = __uint_as_float(u4.w << 16);
                f1[3] = __uint_as_float(u4.w & 0xffff0000u);
                float* dst = Wrow + (size_t)row * S_SZ + c16 * 8;
                __builtin_nontemporal_store(f0, (f32x4*)dst);
                __builtin_nontemporal_store(f1, (f32x4*)(dst + 4));
            }
        }
    }
}

extern "C" void kernel_launch(void* const* d_in, const int* in_sizes, int n_in,
                              void* d_out, int out_size, void* d_ws, size_t ws_size,
                              hipStream_t stream)
{
    const float* Q = (const float*)d_in[0];
    const float* K = (const float*)d_in[1];
    const float* V = (const float*)d_in[2];
    float* ctx = (float*)d_out;
    float* w   = (float*)d_out + (size_t)B_SZ * H_SZ * S_SZ * D_SZ;
    char*  ws  = (char*)d_ws;

    prep_k<<<1024, 256, 0, stream>>>(K, ws);
    prep_v<<<512,  256, 0, stream>>>(V, ws);
    attn_fused6<<<2048, 512, 0, stream>>>(Q, ws, ctx, w);
}

// Round 9
// 256.728 us; speedup vs baseline: 5.5148x; 5.5148x over previous
//
#include <hip/hip_runtime.h>
#include <hip/hip_bf16.h>

#define B_SZ 2
#define H_SZ 16
#define S_SZ 2048
#define D_SZ 64
#define WAVES 8
#define NBH  (B_SZ * H_SZ)      // 32
#define NQB  (S_SZ / 16)        // 128 16-row K blocks per bh
#define NUB  (S_SZ / 32)        // 64 32-row V blocks per bh

typedef __bf16 bf16x8 __attribute__((ext_vector_type(8)));
typedef float  f32x4  __attribute__((ext_vector_type(4)));

// d_ws layout: pre-swizzled bf16 MFMA fragments (8 MB segments)
#define SEG   (8u * 1024u * 1024u)
#define KHI_OFF (0 * (size_t)SEG)
#define KLO_OFF (1 * (size_t)SEG)
#define VSW_OFF (2 * (size_t)SEG)

// ---- prep K: fp32 -> bf16 hi/lo, swizzled to MFMA A-fragment order.
__global__ __launch_bounds__(256) void prep_k(
    const float* __restrict__ K, char* __restrict__ ws)
{
    const int lane = threadIdx.x & 63;
    const int wv   = threadIdx.x >> 6;
    const int l15  = lane & 15;
    const int g    = lane >> 4;
    const int wid  = blockIdx.x * 4 + wv;          // 0..4095
    const int bh   = wid >> 7;
    const int blk  = wid & 127;

    const float* src = K + ((size_t)bh * S_SZ + blk * 16 + l15) * D_SZ;
    bf16x8* hi = (bf16x8*)(ws + KHI_OFF);
    bf16x8* lo = (bf16x8*)(ws + KLO_OFF);

    #pragma unroll
    for (int ks = 0; ks < 2; ++ks) {
        const float* p = src + 32 * ks + 8 * g;
        f32x4 a = *(const f32x4*)p;
        f32x4 b = *(const f32x4*)(p + 4);
        bf16x8 vh, vl;
        #pragma unroll
        for (int j = 0; j < 4; ++j) {
            __bf16 h0 = (__bf16)a[j];
            __bf16 h1 = (__bf16)b[j];
            vh[j]     = h0;
            vh[4 + j] = h1;
            vl[j]     = (__bf16)(a[j] - (float)h0);
            vl[4 + j] = (__bf16)(b[j] - (float)h1);
        }
        size_t di = ((size_t)(bh * NQB + blk) * 2 + ks) * 64 + lane;
        hi[di] = vh;
        lo[di] = vl;
    }
}

// ---- prep V: fp32 -> bf16, B-fragment order with pi-permutation baked in.
__global__ __launch_bounds__(256) void prep_v(
    const float* __restrict__ V, char* __restrict__ ws)
{
    __shared__ float vt[4][32 * 68];
    const int lane = threadIdx.x & 63;
    const int wv   = threadIdx.x >> 6;
    const int l15  = lane & 15;
    const int g    = lane >> 4;
    const int wid  = blockIdx.x * 4 + wv;          // 0..2047
    const int bh   = wid >> 6;
    const int u    = wid & 63;

    const float* src = V + ((size_t)bh * S_SZ + u * 32) * D_SZ;
    float* t = vt[wv];
    #pragma unroll
    for (int i = 0; i < 8; ++i) {
        int idx = i * 64 + lane;
        int row = idx >> 4;
        int c4  = idx & 15;
        *(f32x4*)(t + row * 68 + c4 * 4) = *(const f32x4*)(src + row * 64 + c4 * 4);
    }
    __syncthreads();

    bf16x8* vsw = (bf16x8*)(ws + VSW_OFF);
    #pragma unroll
    for (int db = 0; db < 4; ++db) {
        bf16x8 vb;
        #pragma unroll
        for (int j = 0; j < 8; ++j) {
            int kk = (j < 4) ? (4 * g + j) : (16 + 4 * g + (j - 4));
            vb[j] = (__bf16)t[kk * 68 + 16 * db + l15];
        }
        vsw[((size_t)(bh * NUB + u) * 4 + db) * 64 + lane] = vb;
    }
}

// ---- main fused kernel (R6 structure; sweep uses REGULAR stores).
// One wg = 16 q-rows. QK^T (hi/lo bf16 split) -> softmax -> stage W tile
// in LDS (64 KB, 16B-granule XOR swizzle) -> sweep out row-major with
// plain cached stores (full-line L2 writeback, no NT partial-line
// amplification) -> PV (store drain overlaps V reads) -> ctxred.
__global__ __launch_bounds__(512, 4) void attn_fused7(
    const float* __restrict__ Q, const char* __restrict__ ws,
    float* __restrict__ OutC, float* __restrict__ OutW)
{
    __shared__ __align__(16) char smem[66560];   // 64KB W-tile + redm + reds
    float* redm = (float*)(smem + 65536);        // [8][16]
    float* reds = (float*)(smem + 65536 + 512);  // [8][16]

    const int tid  = threadIdx.x;
    const int lane = tid & 63;
    const int wv   = tid >> 6;
    const int l15  = lane & 15;
    const int g    = lane >> 4;

    // XCD-aware swizzle: XCD x owns bh range [4x, 4x+4)
    const int b    = blockIdx.x;
    const int work = (b & 7) * 512 + (b >> 3);
    const int bh   = work >> 7;
    const int qt   = work & 127;
    const int q0   = qt * 16;

    const bf16x8* KHI = (const bf16x8*)(ws + KHI_OFF);
    const bf16x8* KLO = (const bf16x8*)(ws + KLO_OFF);
    const bf16x8* VSW = (const bf16x8*)(ws + VSW_OFF);

    float* Wb = OutW + (size_t)bh * S_SZ * S_SZ;
    float* Cb = OutC + (size_t)bh * S_SZ * D_SZ;

    // ---- Q fragments: direct fp32 load + hi/lo split (4 KB per wg)
    bf16x8 qhi[2], qlo[2];
    {
        const float* qp = Q + ((size_t)bh * S_SZ + q0 + l15) * D_SZ + 8 * g;
        #pragma unroll
        for (int ks = 0; ks < 2; ++ks) {
            f32x4 a  = *(const f32x4*)(qp + 32 * ks);
            f32x4 b2 = *(const f32x4*)(qp + 32 * ks + 4);
            #pragma unroll
            for (int j = 0; j < 4; ++j) {
                __bf16 h0 = (__bf16)a[j];
                __bf16 h1 = (__bf16)b2[j];
                qhi[ks][j]     = h0;
                qhi[ks][4 + j] = h1;
                qlo[ks][j]     = (__bf16)(a[j]  - (float)h0);
                qlo[ks][4 + j] = (__bf16)(b2[j] - (float)h1);
            }
        }
    }

    // ---- QK^T: 16 col-blocks per wave, 6 MFMA each (3-term bf16 split)
    f32x4 s[16];
    #pragma unroll
    for (int cb = 0; cb < 16; ++cb) {
        size_t bi = ((size_t)(bh * NQB + wv * 16 + cb) * 2) * 64 + lane;
        bf16x8 kh0 = KHI[bi], kh1 = KHI[bi + 64];
        bf16x8 kl0 = KLO[bi], kl1 = KLO[bi + 64];
        f32x4 acc = {0.f, 0.f, 0.f, 0.f};
        acc = __builtin_amdgcn_mfma_f32_16x16x32_bf16(kh0, qhi[0], acc, 0, 0, 0);
        acc = __builtin_amdgcn_mfma_f32_16x16x32_bf16(kh0, qlo[0], acc, 0, 0, 0);
        acc = __builtin_amdgcn_mfma_f32_16x16x32_bf16(kl0, qhi[0], acc, 0, 0, 0);
        acc = __builtin_amdgcn_mfma_f32_16x16x32_bf16(kh1, qhi[1], acc, 0, 0, 0);
        acc = __builtin_amdgcn_mfma_f32_16x16x32_bf16(kh1, qlo[1], acc, 0, 0, 0);
        acc = __builtin_amdgcn_mfma_f32_16x16x32_bf16(kl1, qhi[1], acc, 0, 0, 0);
        s[cb] = acc;
    }

    // ---- row max
    float m = -3.0e38f;
    #pragma unroll
    for (int cb = 0; cb < 16; ++cb) {
        #pragma unroll
        for (int r = 0; r < 4; ++r) m = fmaxf(m, s[cb][r]);
    }
    m = fmaxf(m, __shfl_xor(m, 16));
    m = fmaxf(m, __shfl_xor(m, 32));
    if (lane < 16) redm[wv * 16 + l15] = m;
    __syncthreads();
    float mall = redm[l15];
    #pragma unroll
    for (int w2 = 1; w2 < WAVES; ++w2) mall = fmaxf(mall, redm[w2 * 16 + l15]);

    // ---- exp + row sum
    float sm = 0.f;
    #pragma unroll
    for (int cb = 0; cb < 16; ++cb) {
        #pragma unroll
        for (int r = 0; r < 4; ++r) {
            float e = __expf(s[cb][r] - mall);
            s[cb][r] = e;
            sm += e;
        }
    }
    sm += __shfl_xor(sm, 16);
    sm += __shfl_xor(sm, 32);
    if (lane < 16) reds[wv * 16 + l15] = sm;
    __syncthreads();
    float lsum = 0.f;
    #pragma unroll
    for (int w2 = 0; w2 < WAVES; ++w2) lsum += reds[w2 * 16 + l15];
    const float inv = 1.0f / lsum;

    // ---- normalize -> pack P bf16 -> stage W tile in LDS (frees s[])
    // 16B-granule XOR swizzle: byte = row*4096 + ((c4*8) ^ ((row&7)<<4))
    bf16x8 pa[8];
    const int swz = (l15 & 7) << 4;
    #pragma unroll
    for (int u = 0; u < 8; ++u) {
        f32x4 w0, w1;
        #pragma unroll
        for (int r = 0; r < 4; ++r) {
            w0[r] = s[2 * u][r]     * inv;
            w1[r] = s[2 * u + 1][r] * inv;
        }
        #pragma unroll
        for (int r = 0; r < 4; ++r) {
            pa[u][r]     = (__bf16)w0[r];
            pa[u][4 + r] = (__bf16)w1[r];
        }
        const uint2* pau = (const uint2*)&pa[u];
        int c4a = wv * 64 + (2 * u) * 4 + g;
        int c4b = c4a + 4;
        *(uint2*)(smem + l15 * 4096 + ((c4a * 8) ^ swz)) = pau[0];
        *(uint2*)(smem + l15 * 4096 + ((c4b * 8) ^ swz)) = pau[1];
    }
    __syncthreads();

    // ---- sweep-out: row-major contiguous REGULAR stores (1 KB/wave-instr);
    // L2 gathers full lines -> no partial-line amplification. Store drain
    // overlaps the PV phase below.
    {
        float* Wrow = Wb + (size_t)q0 * S_SZ;
        #pragma unroll
        for (int sidx = 0; sidx < 8; ++sidx) {
            int unit = sidx * 512 + tid;        // 16B units; 256 per row
            int row  = unit >> 8;
            int c16  = unit & 255;
            uint4 u4 = *(const uint4*)(smem + row * 4096 + ((c16 * 16) ^ ((row & 7) << 4)));
            f32x4 f0, f1;
            f0[0] = __uint_as_float(u4.x << 16);
            f0[1] = __uint_as_float(u4.x & 0xffff0000u);
            f0[2] = __uint_as_float(u4.y << 16);
            f0[3] = __uint_as_float(u4.y & 0xffff0000u);
            f1[0] = __uint_as_float(u4.z << 16);
            f1[1] = __uint_as_float(u4.z & 0xffff0000u);
            f1[2] = __uint_as_float(u4.w << 16);
            f1[3] = __uint_as_float(u4.w & 0xffff0000u);
            float* dst = Wrow + (size_t)row * S_SZ + c16 * 8;
            *(f32x4*)dst       = f0;
            *(f32x4*)(dst + 4) = f1;
        }
    }

    // ---- PV: A = packed P, B = pre-permuted V fragments
    f32x4 ctx[4];
    #pragma unroll
    for (int db = 0; db < 4; ++db) ctx[db] = (f32x4){0.f, 0.f, 0.f, 0.f};
    #pragma unroll
    for (int u = 0; u < 8; ++u) {
        size_t vbase = ((size_t)(bh * NUB + wv * 8 + u) * 4) * 64 + lane;
        #pragma unroll
        for (int db = 0; db < 4; ++db) {
            bf16x8 vb = VSW[vbase + (size_t)db * 64];
            ctx[db] = __builtin_amdgcn_mfma_f32_16x16x32_bf16(pa[u], vb, ctx[db], 0, 0, 0);
        }
    }

    // ---- ctx reduction reusing W-LDS
    __syncthreads();                 // sweep reads done; safe to overwrite
    float* ctxred = (float*)smem;    // [8][16][64] = 32 KB
    #pragma unroll
    for (int db = 0; db < 4; ++db) {
        #pragma unroll
        for (int r = 0; r < 4; ++r)
            ctxred[(wv * 16 + 4 * g + r) * 64 + 16 * db + l15] = ctx[db][r];
    }
    __syncthreads();
    {
        const int qr = tid >> 6;
        const int d  = tid & 63;
        float acc0 = 0.f, acc1 = 0.f;
        #pragma unroll
        for (int w2 = 0; w2 < WAVES; ++w2) {
            acc0 += ctxred[(w2 * 16 + qr) * 64 + d];
            acc1 += ctxred[(w2 * 16 + qr + 8) * 64 + d];
        }
        Cb[(size_t)(q0 + qr) * D_SZ + d]     = acc0;
        Cb[(size_t)(q0 + qr + 8) * D_SZ + d] = acc1;
    }
}

extern "C" void kernel_launch(void* const* d_in, const int* in_sizes, int n_in,
                              void* d_out, int out_size, void* d_ws, size_t ws_size,
                              hipStream_t stream)
{
    const float* Q = (const float*)d_in[0];
    const float* K = (const float*)d_in[1];
    const float* V = (const float*)d_in[2];
    float* ctx = (float*)d_out;
    float* w   = (float*)d_out + (size_t)B_SZ * H_SZ * S_SZ * D_SZ;
    char*  ws  = (char*)d_ws;

    prep_k<<<1024, 256, 0, stream>>>(K, ws);
    prep_v<<<512,  256, 0, stream>>>(V, ws);
    attn_fused7<<<4096, 512, 0, stream>>>(Q, ws, ctx, w);
}

// Round 10
// 249.245 us; speedup vs baseline: 5.6804x; 1.0300x over previous
//
#include <hip/hip_runtime.h>
#include <hip/hip_bf16.h>

#define B_SZ 2
#define H_SZ 16
#define S_SZ 2048
#define D_SZ 64
#define WAVES 8
#define NBH  (B_SZ * H_SZ)      // 32
#define NQB  (S_SZ / 16)        // 128 16-row K blocks per bh
#define NUB  (S_SZ / 32)        // 64 32-row V blocks per bh

typedef __bf16 bf16x8 __attribute__((ext_vector_type(8)));
typedef float  f32x4  __attribute__((ext_vector_type(4)));

// d_ws layout: pre-swizzled bf16 MFMA fragments (8 MB segments)
#define SEG   (8u * 1024u * 1024u)
#define KHI_OFF (0 * (size_t)SEG)
#define KLO_OFF (1 * (size_t)SEG)
#define VSW_OFF (2 * (size_t)SEG)

// ---- fused prep: blocks [0,1024) do K (fp32 -> bf16 hi/lo, A-fragment
// order); blocks [1024,1536) do V (bf16, B-fragment order, pi-permuted).
__global__ __launch_bounds__(256) void prep_kv(
    const float* __restrict__ K, const float* __restrict__ V,
    char* __restrict__ ws)
{
    __shared__ float vt[4][32 * 68];
    const int lane = threadIdx.x & 63;
    const int wv   = threadIdx.x >> 6;
    const int l15  = lane & 15;
    const int g    = lane >> 4;

    if (blockIdx.x < 1024) {
        const int wid = blockIdx.x * 4 + wv;       // 0..4095
        const int bh  = wid >> 7;
        const int blk = wid & 127;

        const float* src = K + ((size_t)bh * S_SZ + blk * 16 + l15) * D_SZ;
        bf16x8* hi = (bf16x8*)(ws + KHI_OFF);
        bf16x8* lo = (bf16x8*)(ws + KLO_OFF);

        #pragma unroll
        for (int ks = 0; ks < 2; ++ks) {
            const float* p = src + 32 * ks + 8 * g;
            f32x4 a = *(const f32x4*)p;
            f32x4 b = *(const f32x4*)(p + 4);
            bf16x8 vh, vl;
            #pragma unroll
            for (int j = 0; j < 4; ++j) {
                __bf16 h0 = (__bf16)a[j];
                __bf16 h1 = (__bf16)b[j];
                vh[j]     = h0;
                vh[4 + j] = h1;
                vl[j]     = (__bf16)(a[j] - (float)h0);
                vl[4 + j] = (__bf16)(b[j] - (float)h1);
            }
            size_t di = ((size_t)(bh * NQB + blk) * 2 + ks) * 64 + lane;
            hi[di] = vh;
            lo[di] = vl;
        }
    } else {
        const int wid = (blockIdx.x - 1024) * 4 + wv;   // 0..2047
        const int bh  = wid >> 6;
        const int u   = wid & 63;

        const float* src = V + ((size_t)bh * S_SZ + u * 32) * D_SZ;
        float* t = vt[wv];
        #pragma unroll
        for (int i = 0; i < 8; ++i) {
            int idx = i * 64 + lane;
            int row = idx >> 4;
            int c4  = idx & 15;
            *(f32x4*)(t + row * 68 + c4 * 4) = *(const f32x4*)(src + row * 64 + c4 * 4);
        }
        __syncthreads();

        bf16x8* vsw = (bf16x8*)(ws + VSW_OFF);
        #pragma unroll
        for (int db = 0; db < 4; ++db) {
            bf16x8 vb;
            #pragma unroll
            for (int j = 0; j < 8; ++j) {
                int kk = (j < 4) ? (4 * g + j) : (16 + 4 * g + (j - 4));
                vb[j] = (__bf16)t[kk * 68 + 16 * db + l15];
            }
            vsw[((size_t)(bh * NUB + u) * 4 + db) * 64 + lane] = vb;
        }
    }
}

// ---- main fused kernel (R6-proven structure).
// One wg = 16 q-rows. QK^T (hi/lo bf16 split) -> softmax -> stage W tile
// in LDS (64 KB, 16B-granule XOR swizzle) -> sweep out row-major as a
// dense NT-store burst (write-once stream stays out of L2; full lines
// filled instantly) -> PV (store drain overlaps V reads) -> ctxred.
__global__ __launch_bounds__(512, 4) void attn_fused8(
    const float* __restrict__ Q, const char* __restrict__ ws,
    float* __restrict__ OutC, float* __restrict__ OutW)
{
    __shared__ __align__(16) char smem[66560];   // 64KB W-tile + redm + reds
    float* redm = (float*)(smem + 65536);        // [8][16]
    float* reds = (float*)(smem + 65536 + 512);  // [8][16]

    const int tid  = threadIdx.x;
    const int lane = tid & 63;
    const int wv   = tid >> 6;
    const int l15  = lane & 15;
    const int g    = lane >> 4;

    // XCD-aware swizzle: XCD x owns bh range [4x, 4x+4)
    const int b    = blockIdx.x;
    const int work = (b & 7) * 512 + (b >> 3);
    const int bh   = work >> 7;
    const int qt   = work & 127;
    const int q0   = qt * 16;

    const bf16x8* KHI = (const bf16x8*)(ws + KHI_OFF);
    const bf16x8* KLO = (const bf16x8*)(ws + KLO_OFF);
    const bf16x8* VSW = (const bf16x8*)(ws + VSW_OFF);

    float* Wb = OutW + (size_t)bh * S_SZ * S_SZ;
    float* Cb = OutC + (size_t)bh * S_SZ * D_SZ;

    // ---- Q fragments: direct fp32 load + hi/lo split (4 KB per wg)
    bf16x8 qhi[2], qlo[2];
    {
        const float* qp = Q + ((size_t)bh * S_SZ + q0 + l15) * D_SZ + 8 * g;
        #pragma unroll
        for (int ks = 0; ks < 2; ++ks) {
            f32x4 a  = *(const f32x4*)(qp + 32 * ks);
            f32x4 b2 = *(const f32x4*)(qp + 32 * ks + 4);
            #pragma unroll
            for (int j = 0; j < 4; ++j) {
                __bf16 h0 = (__bf16)a[j];
                __bf16 h1 = (__bf16)b2[j];
                qhi[ks][j]     = h0;
                qhi[ks][4 + j] = h1;
                qlo[ks][j]     = (__bf16)(a[j]  - (float)h0);
                qlo[ks][4 + j] = (__bf16)(b2[j] - (float)h1);
            }
        }
    }

    // ---- QK^T: 16 col-blocks per wave, 6 MFMA each (3-term bf16 split)
    f32x4 s[16];
    #pragma unroll
    for (int cb = 0; cb < 16; ++cb) {
        size_t bi = ((size_t)(bh * NQB + wv * 16 + cb) * 2) * 64 + lane;
        bf16x8 kh0 = KHI[bi], kh1 = KHI[bi + 64];
        bf16x8 kl0 = KLO[bi], kl1 = KLO[bi + 64];
        f32x4 acc = {0.f, 0.f, 0.f, 0.f};
        acc = __builtin_amdgcn_mfma_f32_16x16x32_bf16(kh0, qhi[0], acc, 0, 0, 0);
        acc = __builtin_amdgcn_mfma_f32_16x16x32_bf16(kh0, qlo[0], acc, 0, 0, 0);
        acc = __builtin_amdgcn_mfma_f32_16x16x32_bf16(kl0, qhi[0], acc, 0, 0, 0);
        acc = __builtin_amdgcn_mfma_f32_16x16x32_bf16(kh1, qhi[1], acc, 0, 0, 0);
        acc = __builtin_amdgcn_mfma_f32_16x16x32_bf16(kh1, qlo[1], acc, 0, 0, 0);
        acc = __builtin_amdgcn_mfma_f32_16x16x32_bf16(kl1, qhi[1], acc, 0, 0, 0);
        s[cb] = acc;
    }

    // ---- row max
    float m = -3.0e38f;
    #pragma unroll
    for (int cb = 0; cb < 16; ++cb) {
        #pragma unroll
        for (int r = 0; r < 4; ++r) m = fmaxf(m, s[cb][r]);
    }
    m = fmaxf(m, __shfl_xor(m, 16));
    m = fmaxf(m, __shfl_xor(m, 32));
    if (lane < 16) redm[wv * 16 + l15] = m;
    __syncthreads();
    float mall = redm[l15];
    #pragma unroll
    for (int w2 = 1; w2 < WAVES; ++w2) mall = fmaxf(mall, redm[w2 * 16 + l15]);

    // ---- exp + row sum
    float sm = 0.f;
    #pragma unroll
    for (int cb = 0; cb < 16; ++cb) {
        #pragma unroll
        for (int r = 0; r < 4; ++r) {
            float e = __expf(s[cb][r] - mall);
            s[cb][r] = e;
            sm += e;
        }
    }
    sm += __shfl_xor(sm, 16);
    sm += __shfl_xor(sm, 32);
    if (lane < 16) reds[wv * 16 + l15] = sm;
    __syncthreads();
    float lsum = 0.f;
    #pragma unroll
    for (int w2 = 0; w2 < WAVES; ++w2) lsum += reds[w2 * 16 + l15];
    const float inv = 1.0f / lsum;

    // ---- normalize -> pack P bf16 -> stage W tile in LDS (frees s[])
    // 16B-granule XOR swizzle: byte = row*4096 + ((c4*8) ^ ((row&7)<<4))
    bf16x8 pa[8];
    const int swz = (l15 & 7) << 4;
    #pragma unroll
    for (int u = 0; u < 8; ++u) {
        f32x4 w0, w1;
        #pragma unroll
        for (int r = 0; r < 4; ++r) {
            w0[r] = s[2 * u][r]     * inv;
            w1[r] = s[2 * u + 1][r] * inv;
        }
        #pragma unroll
        for (int r = 0; r < 4; ++r) {
            pa[u][r]     = (__bf16)w0[r];
            pa[u][4 + r] = (__bf16)w1[r];
        }
        const uint2* pau = (const uint2*)&pa[u];
        int c4a = wv * 64 + (2 * u) * 4 + g;
        int c4b = c4a + 4;
        *(uint2*)(smem + l15 * 4096 + ((c4a * 8) ^ swz)) = pau[0];
        *(uint2*)(smem + l15 * 4096 + ((c4b * 8) ^ swz)) = pau[1];
    }
    __syncthreads();

    // ---- sweep-out: row-major contiguous NT-store burst (1 KB/wave-instr);
    // write-once W stream bypasses L2 (protects K/V fragment residency);
    // dense burst fills whole lines. Drain overlaps the PV phase below.
    {
        float* Wrow = Wb + (size_t)q0 * S_SZ;
        #pragma unroll
        for (int sidx = 0; sidx < 8; ++sidx) {
            int unit = sidx * 512 + tid;        // 16B units; 256 per row
            int row  = unit >> 8;
            int c16  = unit & 255;
            uint4 u4 = *(const uint4*)(smem + row * 4096 + ((c16 * 16) ^ ((row & 7) << 4)));
            f32x4 f0, f1;
            f0[0] = __uint_as_float(u4.x << 16);
            f0[1] = __uint_as_float(u4.x & 0xffff0000u);
            f0[2] = __uint_as_float(u4.y << 16);
            f0[3] = __uint_as_float(u4.y & 0xffff0000u);
            f1[0] = __uint_as_float(u4.z << 16);
            f1[1] = __uint_as_float(u4.z & 0xffff0000u);
            f1[2] = __uint_as_float(u4.w << 16);
            f1[3] = __uint_as_float(u4.w & 0xffff0000u);
            float* dst = Wrow + (size_t)row * S_SZ + c16 * 8;
            __builtin_nontemporal_store(f0, (f32x4*)dst);
            __builtin_nontemporal_store(f1, (f32x4*)(dst + 4));
        }
    }

    // ---- PV: A = packed P, B = pre-permuted V fragments
    f32x4 ctx[4];
    #pragma unroll
    for (int db = 0; db < 4; ++db) ctx[db] = (f32x4){0.f, 0.f, 0.f, 0.f};
    #pragma unroll
    for (int u = 0; u < 8; ++u) {
        size_t vbase = ((size_t)(bh * NUB + wv * 8 + u) * 4) * 64 + lane;
        #pragma unroll
        for (int db = 0; db < 4; ++db) {
            bf16x8 vb = VSW[vbase + (size_t)db * 64];
            ctx[db] = __builtin_amdgcn_mfma_f32_16x16x32_bf16(pa[u], vb, ctx[db], 0, 0, 0);
        }
    }

    // ---- ctx reduction reusing W-LDS
    __syncthreads();                 // sweep reads done; safe to overwrite
    float* ctxred = (float*)smem;    // [8][16][64] = 32 KB
    #pragma unroll
    for (int db = 0; db < 4; ++db) {
        #pragma unroll
        for (int r = 0; r < 4; ++r)
            ctxred[(wv * 16 + 4 * g + r) * 64 + 16 * db + l15] = ctx[db][r];
    }
    __syncthreads();
    {
        const int qr = tid >> 6;
        const int d  = tid & 63;
        float acc0 = 0.f, acc1 = 0.f;
        #pragma unroll
        for (int w2 = 0; w2 < WAVES; ++w2) {
            acc0 += ctxred[(w2 * 16 + qr) * 64 + d];
            acc1 += ctxred[(w2 * 16 + qr + 8) * 64 + d];
        }
        __builtin_nontemporal_store(acc0, Cb + (size_t)(q0 + qr) * D_SZ + d);
        __builtin_nontemporal_store(acc1, Cb + (size_t)(q0 + qr + 8) * D_SZ + d);
    }
}

extern "C" void kernel_launch(void* const* d_in, const int* in_sizes, int n_in,
                              void* d_out, int out_size, void* d_ws, size_t ws_size,
                              hipStream_t stream)
{
    const float* Q = (const float*)d_in[0];
    const float* K = (const float*)d_in[1];
    const float* V = (const float*)d_in[2];
    float* ctx = (float*)d_out;
    float* w   = (float*)d_out + (size_t)B_SZ * H_SZ * S_SZ * D_SZ;
    char*  ws  = (char*)d_ws;

    prep_kv<<<1536, 256, 0, stream>>>(K, V, ws);
    attn_fused8<<<4096, 512, 0, stream>>>(Q, ws, ctx, w);
}

// Round 11
// 184.188 us; speedup vs baseline: 7.6867x; 1.3532x over previous
//
#include <hip/hip_runtime.h>
#include <hip/hip_bf16.h>

#define B_SZ 2
#define H_SZ 16
#define S_SZ 2048
#define D_SZ 64
#define WAVES 8
#define NBH  (B_SZ * H_SZ)      // 32
#define NQB  (S_SZ / 16)        // 128 16-row blocks
#define NUB  (S_SZ / 32)        // 64 32-row V blocks

typedef __bf16 bf16x8 __attribute__((ext_vector_type(8)));
typedef float  f32x4  __attribute__((ext_vector_type(4)));

// d_ws layout: pre-swizzled bf16 MFMA fragments (8 MB segments)
#define SEG   (8u * 1024u * 1024u)
#define QHI_OFF (0 * (size_t)SEG)
#define QLO_OFF (1 * (size_t)SEG)
#define KHI_OFF (2 * (size_t)SEG)
#define KLO_OFF (3 * (size_t)SEG)
#define VSW_OFF (4 * (size_t)SEG)

// ---- prep Q/K: fp32 -> bf16 hi/lo, swizzled to A/B fragment order.
__global__ __launch_bounds__(256) void prep_qk(
    const float* __restrict__ Q, const float* __restrict__ K,
    char* __restrict__ ws)
{
    const int lane = threadIdx.x & 63;
    const int wv   = threadIdx.x >> 6;
    const int l15  = lane & 15;
    const int g    = lane >> 4;
    const int wid  = blockIdx.x * 4 + wv;          // 0..8191
    const int tensor = wid >> 12;
    const int rem  = wid & 4095;
    const int bh   = rem >> 7;
    const int blk  = rem & 127;

    const float* src = (tensor ? K : Q) + ((size_t)bh * S_SZ + blk * 16 + l15) * D_SZ;
    bf16x8* hi = (bf16x8*)(ws + (tensor ? KHI_OFF : QHI_OFF));
    bf16x8* lo = (bf16x8*)(ws + (tensor ? KLO_OFF : QLO_OFF));

    #pragma unroll
    for (int ks = 0; ks < 2; ++ks) {
        const float* p = src + 32 * ks + 8 * g;
        f32x4 a = *(const f32x4*)p;
        f32x4 b = *(const f32x4*)(p + 4);
        bf16x8 vh, vl;
        #pragma unroll
        for (int j = 0; j < 4; ++j) {
            __bf16 h0 = (__bf16)a[j];
            __bf16 h1 = (__bf16)b[j];
            vh[j]     = h0;
            vh[4 + j] = h1;
            vl[j]     = (__bf16)(a[j] - (float)h0);
            vl[4 + j] = (__bf16)(b[j] - (float)h1);
        }
        size_t di = ((size_t)(bh * NQB + blk) * 2 + ks) * 64 + lane;
        hi[di] = vh;
        lo[di] = vl;
    }
}

// ---- prep V: fp32 -> bf16, B-fragment order with pi-permutation baked in.
__global__ __launch_bounds__(256) void prep_v(
    const float* __restrict__ V, char* __restrict__ ws)
{
    __shared__ float vt[4][32 * 68];
    const int lane = threadIdx.x & 63;
    const int wv   = threadIdx.x >> 6;
    const int l15  = lane & 15;
    const int g    = lane >> 4;
    const int wid  = blockIdx.x * 4 + wv;          // 0..2047
    const int bh   = wid >> 6;
    const int u    = wid & 63;

    const float* src = V + ((size_t)bh * S_SZ + u * 32) * D_SZ;
    float* t = vt[wv];
    #pragma unroll
    for (int i = 0; i < 8; ++i) {
        int idx = i * 64 + lane;
        int row = idx >> 4;
        int c4  = idx & 15;
        *(f32x4*)(t + row * 68 + c4 * 4) = *(const f32x4*)(src + row * 64 + c4 * 4);
    }
    __syncthreads();

    bf16x8* vsw = (bf16x8*)(ws + VSW_OFF);
    #pragma unroll
    for (int db = 0; db < 4; ++db) {
        bf16x8 vb;
        #pragma unroll
        for (int j = 0; j < 8; ++j) {
            int kk = (j < 4) ? (4 * g + j) : (16 + 4 * g + (j - 4));
            vb[j] = (__bf16)t[kk * 68 + 16 * db + l15];
        }
        vsw[((size_t)(bh * NUB + u) * 4 + db) * 64 + lane] = vb;
    }
}

// ---- main fused kernel (R6-exact: best known, 185 us).
// One wg = 16 q-rows. QK^T (hi/lo bf16 split, ws-sourced Q fragments) ->
// softmax -> stage W tile in LDS (64 KB, XOR swizzle) -> dense NT-burst
// sweep row-major -> PV (store drain overlaps V reads) -> ctxred.
__global__ __launch_bounds__(512, 4) void attn_fused4(
    const char* __restrict__ ws, float* __restrict__ OutC, float* __restrict__ OutW)
{
    __shared__ __align__(16) char smem[66560];   // 64KB W-tile + redm + reds
    float* redm = (float*)(smem + 65536);        // [8][16]
    float* reds = (float*)(smem + 65536 + 512);  // [8][16]

    const int tid  = threadIdx.x;
    const int lane = tid & 63;
    const int wv   = tid >> 6;
    const int l15  = lane & 15;
    const int g    = lane >> 4;

    // XCD-aware swizzle: XCD x owns bh range [4x, 4x+4)
    const int b    = blockIdx.x;
    const int work = (b & 7) * 512 + (b >> 3);
    const int bh   = work >> 7;
    const int qt   = work & 127;
    const int q0   = qt * 16;

    const bf16x8* QHI = (const bf16x8*)(ws + QHI_OFF);
    const bf16x8* QLO = (const bf16x8*)(ws + QLO_OFF);
    const bf16x8* KHI = (const bf16x8*)(ws + KHI_OFF);
    const bf16x8* KLO = (const bf16x8*)(ws + KLO_OFF);
    const bf16x8* VSW = (const bf16x8*)(ws + VSW_OFF);

    float* Wb = OutW + (size_t)bh * S_SZ * S_SZ;
    float* Cb = OutC + (size_t)bh * S_SZ * D_SZ;

    // Q fragments
    bf16x8 qhi[2], qlo[2];
    {
        size_t qi = ((size_t)(bh * NQB + qt) * 2) * 64 + lane;
        qhi[0] = QHI[qi];       qhi[1] = QHI[qi + 64];
        qlo[0] = QLO[qi];       qlo[1] = QLO[qi + 64];
    }

    // QK^T: 16 col-blocks per wave, 6 MFMA each (3-term bf16 split)
    f32x4 s[16];
    const int kb0 = wv * 16;
    #pragma unroll
    for (int cb = 0; cb < 16; ++cb) {
        size_t bi = ((size_t)(bh * NQB + kb0 + cb) * 2) * 64 + lane;
        bf16x8 kh0 = KHI[bi], kh1 = KHI[bi + 64];
        bf16x8 kl0 = KLO[bi], kl1 = KLO[bi + 64];
        f32x4 acc = {0.f, 0.f, 0.f, 0.f};
        acc = __builtin_amdgcn_mfma_f32_16x16x32_bf16(kh0, qhi[0], acc, 0, 0, 0);
        acc = __builtin_amdgcn_mfma_f32_16x16x32_bf16(kh0, qlo[0], acc, 0, 0, 0);
        acc = __builtin_amdgcn_mfma_f32_16x16x32_bf16(kl0, qhi[0], acc, 0, 0, 0);
        acc = __builtin_amdgcn_mfma_f32_16x16x32_bf16(kh1, qhi[1], acc, 0, 0, 0);
        acc = __builtin_amdgcn_mfma_f32_16x16x32_bf16(kh1, qlo[1], acc, 0, 0, 0);
        acc = __builtin_amdgcn_mfma_f32_16x16x32_bf16(kl1, qhi[1], acc, 0, 0, 0);
        s[cb] = acc;
    }

    // row max
    float m = -3.0e38f;
    #pragma unroll
    for (int cb = 0; cb < 16; ++cb) {
        #pragma unroll
        for (int r = 0; r < 4; ++r) m = fmaxf(m, s[cb][r]);
    }
    m = fmaxf(m, __shfl_xor(m, 16));
    m = fmaxf(m, __shfl_xor(m, 32));
    if (lane < 16) redm[wv * 16 + l15] = m;
    __syncthreads();
    float mall = redm[l15];
    #pragma unroll
    for (int w2 = 1; w2 < WAVES; ++w2) mall = fmaxf(mall, redm[w2 * 16 + l15]);

    // exp + row sum
    float sm = 0.f;
    #pragma unroll
    for (int cb = 0; cb < 16; ++cb) {
        #pragma unroll
        for (int r = 0; r < 4; ++r) {
            float e = __expf(s[cb][r] - mall);
            s[cb][r] = e;
            sm += e;
        }
    }
    sm += __shfl_xor(sm, 16);
    sm += __shfl_xor(sm, 32);
    if (lane < 16) reds[wv * 16 + l15] = sm;
    __syncthreads();
    float lsum = 0.f;
    #pragma unroll
    for (int w2 = 0; w2 < WAVES; ++w2) lsum += reds[w2 * 16 + l15];
    const float inv = 1.0f / lsum;

    // normalize -> pack P to bf16 -> stage W tile in LDS (frees s[])
    // LDS tile: row l15 (4096 B/row), 8B unit c4 = wv*64 + cb*4 + g,
    // byte = row*4096 + ((c4*8) ^ ((row&7)<<4))
    bf16x8 pa[8];
    const int swz = (l15 & 7) << 4;
    #pragma unroll
    for (int u = 0; u < 8; ++u) {
        f32x4 w0, w1;
        #pragma unroll
        for (int r = 0; r < 4; ++r) {
            w0[r] = s[2 * u][r]     * inv;
            w1[r] = s[2 * u + 1][r] * inv;
        }
        #pragma unroll
        for (int r = 0; r < 4; ++r) {
            pa[u][r]     = (__bf16)w0[r];
            pa[u][4 + r] = (__bf16)w1[r];
        }
        const uint2* pau = (const uint2*)&pa[u];
        int c4a = wv * 64 + (2 * u) * 4 + g;
        int c4b = c4a + 4;
        *(uint2*)(smem + l15 * 4096 + ((c4a * 8) ^ swz)) = pau[0];
        *(uint2*)(smem + l15 * 4096 + ((c4b * 8) ^ swz)) = pau[1];
    }
    __syncthreads();

    // sweep-out: row-major contiguous NT stores (1 KB per wave-instruction)
    {
        float* Wrow = Wb + (size_t)q0 * S_SZ;
        #pragma unroll
        for (int sidx = 0; sidx < 16; ++sidx) {
            int unit = sidx * 512 + tid;           // 8B units; 512 units/row
            int row  = unit >> 9;
            int c4   = unit & 511;
            uint2 u2 = *(const uint2*)(smem + row * 4096 + ((c4 * 8) ^ ((row & 7) << 4)));
            f32x4 f;
            f[0] = __uint_as_float(u2.x << 16);
            f[1] = __uint_as_float(u2.x & 0xffff0000u);
            f[2] = __uint_as_float(u2.y << 16);
            f[3] = __uint_as_float(u2.y & 0xffff0000u);
            __builtin_nontemporal_store(f, (f32x4*)(Wrow + (size_t)row * S_SZ + c4 * 4));
        }
    }

    // PV: A = packed P, B = pre-permuted V fragments (no LDS use here)
    f32x4 ctx[4];
    #pragma unroll
    for (int db = 0; db < 4; ++db) ctx[db] = (f32x4){0.f, 0.f, 0.f, 0.f};

    #pragma unroll
    for (int u = 0; u < 8; ++u) {
        size_t vbase = ((size_t)(bh * NUB + wv * 8 + u) * 4) * 64 + lane;
        #pragma unroll
        for (int db = 0; db < 4; ++db) {
            bf16x8 vb = VSW[vbase + (size_t)db * 64];
            ctx[db] = __builtin_amdgcn_mfma_f32_16x16x32_bf16(pa[u], vb, ctx[db], 0, 0, 0);
        }
    }

    // reuse W-tile LDS for cross-wave context reduction
    __syncthreads();                 // all sweep reads complete before overwrite
    float* ctxred = (float*)smem;    // [8][16][64]
    #pragma unroll
    for (int db = 0; db < 4; ++db) {
        #pragma unroll
        for (int r = 0; r < 4; ++r)
            ctxred[(wv * 16 + 4 * g + r) * 64 + 16 * db + l15] = ctx[db][r];
    }
    __syncthreads();
    {
        const int qr = tid >> 6;
        const int d  = tid & 63;
        float acc0 = 0.f, acc1 = 0.f;
        #pragma unroll
        for (int w2 = 0; w2 < WAVES; ++w2) {
            acc0 += ctxred[(w2 * 16 + qr) * 64 + d];
            acc1 += ctxred[(w2 * 16 + qr + 8) * 64 + d];
        }
        __builtin_nontemporal_store(acc0, Cb + (size_t)(q0 + qr) * D_SZ + d);
        __builtin_nontemporal_store(acc1, Cb + (size_t)(q0 + qr + 8) * D_SZ + d);
    }
}

extern "C" void kernel_launch(void* const* d_in, const int* in_sizes, int n_in,
                              void* d_out, int out_size, void* d_ws, size_t ws_size,
                              hipStream_t stream)
{
    const float* Q = (const float*)d_in[0];
    const float* K = (const float*)d_in[1];
    const float* V = (const float*)d_in[2];
    float* ctx = (float*)d_out;
    float* w   = (float*)d_out + (size_t)B_SZ * H_SZ * S_SZ * D_SZ;
    char*  ws  = (char*)d_ws;

    prep_qk<<<2048, 256, 0, stream>>>(Q, K, ws);
    prep_v <<<512,  256, 0, stream>>>(V, ws);
    attn_fused4<<<4096, 512, 0, stream>>>(ws, ctx, w);
}

// Round 12
// 150.489 us; speedup vs baseline: 9.4080x; 1.2239x over previous
//
#include <hip/hip_runtime.h>
#include <hip/hip_bf16.h>

#define B_SZ 2
#define H_SZ 16
#define S_SZ 2048
#define D_SZ 64
#define WAVES 8
#define NBH  (B_SZ * H_SZ)      // 32
#define NQB  (S_SZ / 16)        // 128 16-row blocks
#define NUB  (S_SZ / 32)        // 64 32-row V blocks

typedef _Float16 half8 __attribute__((ext_vector_type(8)));
typedef _Float16 half4 __attribute__((ext_vector_type(4)));
typedef float    f32x4 __attribute__((ext_vector_type(4)));

// d_ws layout: pre-swizzled fp16 MFMA fragments (8 MB segments)
#define SEG   (8u * 1024u * 1024u)
#define QF_OFF  (0 * (size_t)SEG)
#define KF_OFF  (1 * (size_t)SEG)
#define VSW_OFF (2 * (size_t)SEG)

// ---- prep Q/K: fp32 -> fp16, swizzled to A/B fragment order.
__global__ __launch_bounds__(256) void prep_qk(
    const float* __restrict__ Q, const float* __restrict__ K,
    char* __restrict__ ws)
{
    const int lane = threadIdx.x & 63;
    const int wv   = threadIdx.x >> 6;
    const int l15  = lane & 15;
    const int g    = lane >> 4;
    const int wid  = blockIdx.x * 4 + wv;          // 0..8191
    const int tensor = wid >> 12;
    const int rem  = wid & 4095;
    const int bh   = rem >> 7;
    const int blk  = rem & 127;

    const float* src = (tensor ? K : Q) + ((size_t)bh * S_SZ + blk * 16 + l15) * D_SZ;
    half8* dst = (half8*)(ws + (tensor ? KF_OFF : QF_OFF));

    #pragma unroll
    for (int ks = 0; ks < 2; ++ks) {
        const float* p = src + 32 * ks + 8 * g;
        f32x4 a = *(const f32x4*)p;
        f32x4 b = *(const f32x4*)(p + 4);
        half8 v;
        #pragma unroll
        for (int j = 0; j < 4; ++j) {
            v[j]     = (_Float16)a[j];
            v[4 + j] = (_Float16)b[j];
        }
        dst[((size_t)(bh * NQB + blk) * 2 + ks) * 64 + lane] = v;
    }
}

// ---- prep V: fp32 -> fp16, B-fragment order with pi-permutation baked in.
__global__ __launch_bounds__(256) void prep_v(
    const float* __restrict__ V, char* __restrict__ ws)
{
    __shared__ float vt[4][32 * 68];
    const int lane = threadIdx.x & 63;
    const int wv   = threadIdx.x >> 6;
    const int l15  = lane & 15;
    const int g    = lane >> 4;
    const int wid  = blockIdx.x * 4 + wv;          // 0..2047
    const int bh   = wid >> 6;
    const int u    = wid & 63;

    const float* src = V + ((size_t)bh * S_SZ + u * 32) * D_SZ;
    float* t = vt[wv];
    #pragma unroll
    for (int i = 0; i < 8; ++i) {
        int idx = i * 64 + lane;
        int row = idx >> 4;
        int c4  = idx & 15;
        *(f32x4*)(t + row * 68 + c4 * 4) = *(const f32x4*)(src + row * 64 + c4 * 4);
    }
    __syncthreads();

    half8* vsw = (half8*)(ws + VSW_OFF);
    #pragma unroll
    for (int db = 0; db < 4; ++db) {
        half8 vb;
        #pragma unroll
        for (int j = 0; j < 8; ++j) {
            int kk = (j < 4) ? (4 * g + j) : (16 + 4 * g + (j - 4));
            vb[j] = (_Float16)t[kk * 68 + 16 * db + l15];
        }
        vsw[((size_t)(bh * NUB + u) * 4 + db) * 64 + lane] = vb;
    }
}

// ---- main fused kernel (R6 skeleton, fp16 operands).
// One wg = 16 q-rows. QK^T: fp16 MFMA, 2 per col-block (K reads halved vs
// bf16 hi/lo split; score err ~0.002, negligible). softmax -> stage W tile
// in LDS fp16 (64 KB, XOR swizzle) -> dense NT-burst sweep row-major ->
// PV fp16 (store drain overlaps V reads) -> ctxred.
__global__ __launch_bounds__(512, 4) void attn_fused9(
    const char* __restrict__ ws, float* __restrict__ OutC, float* __restrict__ OutW)
{
    __shared__ __align__(16) char smem[66560];   // 64KB W-tile + redm + reds
    float* redm = (float*)(smem + 65536);        // [8][16]
    float* reds = (float*)(smem + 65536 + 512);  // [8][16]

    const int tid  = threadIdx.x;
    const int lane = tid & 63;
    const int wv   = tid >> 6;
    const int l15  = lane & 15;
    const int g    = lane >> 4;

    // XCD-aware swizzle: XCD x owns bh range [4x, 4x+4)
    const int b    = blockIdx.x;
    const int work = (b & 7) * 512 + (b >> 3);
    const int bh   = work >> 7;
    const int qt   = work & 127;
    const int q0   = qt * 16;

    const half8* QF  = (const half8*)(ws + QF_OFF);
    const half8* KF  = (const half8*)(ws + KF_OFF);
    const half8* VSW = (const half8*)(ws + VSW_OFF);

    float* Wb = OutW + (size_t)bh * S_SZ * S_SZ;
    float* Cb = OutC + (size_t)bh * S_SZ * D_SZ;

    // Q fragments
    half8 qf[2];
    {
        size_t qi = ((size_t)(bh * NQB + qt) * 2) * 64 + lane;
        qf[0] = QF[qi];       qf[1] = QF[qi + 64];
    }

    // QK^T: 16 col-blocks per wave, 2 fp16 MFMA each (K=64 over 2 k-steps)
    f32x4 s[16];
    const int kb0 = wv * 16;
    #pragma unroll
    for (int cb = 0; cb < 16; ++cb) {
        size_t bi = ((size_t)(bh * NQB + kb0 + cb) * 2) * 64 + lane;
        half8 kf0 = KF[bi], kf1 = KF[bi + 64];
        f32x4 acc = {0.f, 0.f, 0.f, 0.f};
        acc = __builtin_amdgcn_mfma_f32_16x16x32_f16(kf0, qf[0], acc, 0, 0, 0);
        acc = __builtin_amdgcn_mfma_f32_16x16x32_f16(kf1, qf[1], acc, 0, 0, 0);
        s[cb] = acc;
    }

    // row max
    float m = -3.0e38f;
    #pragma unroll
    for (int cb = 0; cb < 16; ++cb) {
        #pragma unroll
        for (int r = 0; r < 4; ++r) m = fmaxf(m, s[cb][r]);
    }
    m = fmaxf(m, __shfl_xor(m, 16));
    m = fmaxf(m, __shfl_xor(m, 32));
    if (lane < 16) redm[wv * 16 + l15] = m;
    __syncthreads();
    float mall = redm[l15];
    #pragma unroll
    for (int w2 = 1; w2 < WAVES; ++w2) mall = fmaxf(mall, redm[w2 * 16 + l15]);

    // exp + row sum
    float sm = 0.f;
    #pragma unroll
    for (int cb = 0; cb < 16; ++cb) {
        #pragma unroll
        for (int r = 0; r < 4; ++r) {
            float e = __expf(s[cb][r] - mall);
            s[cb][r] = e;
            sm += e;
        }
    }
    sm += __shfl_xor(sm, 16);
    sm += __shfl_xor(sm, 32);
    if (lane < 16) reds[wv * 16 + l15] = sm;
    __syncthreads();
    float lsum = 0.f;
    #pragma unroll
    for (int w2 = 0; w2 < WAVES; ++w2) lsum += reds[w2 * 16 + l15];
    const float inv = 1.0f / lsum;

    // normalize -> pack P to fp16 -> stage W tile in LDS (frees s[])
    // LDS tile: row l15 (4096 B/row), 8B unit c4 = wv*64 + cb*4 + g,
    // byte = row*4096 + ((c4*8) ^ ((row&7)<<4))
    half8 pa[8];
    const int swz = (l15 & 7) << 4;
    #pragma unroll
    for (int u = 0; u < 8; ++u) {
        f32x4 w0, w1;
        #pragma unroll
        for (int r = 0; r < 4; ++r) {
            w0[r] = s[2 * u][r]     * inv;
            w1[r] = s[2 * u + 1][r] * inv;
        }
        #pragma unroll
        for (int r = 0; r < 4; ++r) {
            pa[u][r]     = (_Float16)w0[r];
            pa[u][4 + r] = (_Float16)w1[r];
        }
        const uint2* pau = (const uint2*)&pa[u];
        int c4a = wv * 64 + (2 * u) * 4 + g;
        int c4b = c4a + 4;
        *(uint2*)(smem + l15 * 4096 + ((c4a * 8) ^ swz)) = pau[0];
        *(uint2*)(smem + l15 * 4096 + ((c4b * 8) ^ swz)) = pau[1];
    }
    __syncthreads();

    // sweep-out: row-major contiguous NT stores (1 KB per wave-instruction)
    {
        float* Wrow = Wb + (size_t)q0 * S_SZ;
        #pragma unroll
        for (int sidx = 0; sidx < 16; ++sidx) {
            int unit = sidx * 512 + tid;           // 8B units; 512 units/row
            int row  = unit >> 9;
            int c4   = unit & 511;
            half4 hv = *(const half4*)(smem + row * 4096 + ((c4 * 8) ^ ((row & 7) << 4)));
            f32x4 f;
            #pragma unroll
            for (int j = 0; j < 4; ++j) f[j] = (float)hv[j];
            __builtin_nontemporal_store(f, (f32x4*)(Wrow + (size_t)row * S_SZ + c4 * 4));
        }
    }

    // PV: A = packed P (fp16), B = pre-permuted V fragments (fp16)
    f32x4 ctx[4];
    #pragma unroll
    for (int db = 0; db < 4; ++db) ctx[db] = (f32x4){0.f, 0.f, 0.f, 0.f};

    #pragma unroll
    for (int u = 0; u < 8; ++u) {
        size_t vbase = ((size_t)(bh * NUB + wv * 8 + u) * 4) * 64 + lane;
        #pragma unroll
        for (int db = 0; db < 4; ++db) {
            half8 vb = VSW[vbase + (size_t)db * 64];
            ctx[db] = __builtin_amdgcn_mfma_f32_16x16x32_f16(pa[u], vb, ctx[db], 0, 0, 0);
        }
    }

    // reuse W-tile LDS for cross-wave context reduction
    __syncthreads();                 // all sweep reads complete before overwrite
    float* ctxred = (float*)smem;    // [8][16][64]
    #pragma unroll
    for (int db = 0; db < 4; ++db) {
        #pragma unroll
        for (int r = 0; r < 4; ++r)
            ctxred[(wv * 16 + 4 * g + r) * 64 + 16 * db + l15] = ctx[db][r];
    }
    __syncthreads();
    {
        const int qr = tid >> 6;
        const int d  = tid & 63;
        float acc0 = 0.f, acc1 = 0.f;
        #pragma unroll
        for (int w2 = 0; w2 < WAVES; ++w2) {
            acc0 += ctxred[(w2 * 16 + qr) * 64 + d];
            acc1 += ctxred[(w2 * 16 + qr + 8) * 64 + d];
        }
        __builtin_nontemporal_store(acc0, Cb + (size_t)(q0 + qr) * D_SZ + d);
        __builtin_nontemporal_store(acc1, Cb + (size_t)(q0 + qr + 8) * D_SZ + d);
    }
}

extern "C" void kernel_launch(void* const* d_in, const int* in_sizes, int n_in,
                              void* d_out, int out_size, void* d_ws, size_t ws_size,
                              hipStream_t stream)
{
    const float* Q = (const float*)d_in[0];
    const float* K = (const float*)d_in[1];
    const float* V = (const float*)d_in[2];
    float* ctx = (float*)d_out;
    float* w   = (float*)d_out + (size_t)B_SZ * H_SZ * S_SZ * D_SZ;
    char*  ws  = (char*)d_ws;

    prep_qk<<<2048, 256, 0, stream>>>(Q, K, ws);
    prep_v <<<512,  256, 0, stream>>>(V, ws);
    attn_fused9<<<4096, 512, 0, stream>>>(ws, ctx, w);
}

// Round 13
// 148.897 us; speedup vs baseline: 9.5086x; 1.0107x over previous
//
#include <hip/hip_runtime.h>
#include <hip/hip_bf16.h>

#define B_SZ 2
#define H_SZ 16
#define S_SZ 2048
#define D_SZ 64
#define WAVES 8
#define NBH  (B_SZ * H_SZ)      // 32
#define NQB  (S_SZ / 16)        // 128 16-row blocks
#define NUB  (S_SZ / 32)        // 64 32-row V blocks

typedef _Float16 half8 __attribute__((ext_vector_type(8)));
typedef _Float16 half4 __attribute__((ext_vector_type(4)));
typedef float    f32x4 __attribute__((ext_vector_type(4)));

// d_ws layout: pre-swizzled fp16 MFMA fragments (8 MB segments)
#define SEG   (8u * 1024u * 1024u)
#define QF_OFF  (0 * (size_t)SEG)
#define KF_OFF  (1 * (size_t)SEG)
#define VSW_OFF (2 * (size_t)SEG)

// ---- fused prep: blocks [0,2048) convert Q/K to fp16 fragments;
// blocks [2048,2560) build pi-permuted V fragments via LDS transpose.
__global__ __launch_bounds__(256) void prep_qkv(
    const float* __restrict__ Q, const float* __restrict__ K,
    const float* __restrict__ V, char* __restrict__ ws)
{
    __shared__ float vt[4][32 * 68];
    const int lane = threadIdx.x & 63;
    const int wv   = threadIdx.x >> 6;
    const int l15  = lane & 15;
    const int g    = lane >> 4;

    if (blockIdx.x < 2048) {
        const int wid  = blockIdx.x * 4 + wv;      // 0..8191
        const int tensor = wid >> 12;
        const int rem  = wid & 4095;
        const int bh   = rem >> 7;
        const int blk  = rem & 127;

        const float* src = (tensor ? K : Q) + ((size_t)bh * S_SZ + blk * 16 + l15) * D_SZ;
        half8* dst = (half8*)(ws + (tensor ? KF_OFF : QF_OFF));

        #pragma unroll
        for (int ks = 0; ks < 2; ++ks) {
            const float* p = src + 32 * ks + 8 * g;
            f32x4 a = *(const f32x4*)p;
            f32x4 b = *(const f32x4*)(p + 4);
            half8 v;
            #pragma unroll
            for (int j = 0; j < 4; ++j) {
                v[j]     = (_Float16)a[j];
                v[4 + j] = (_Float16)b[j];
            }
            dst[((size_t)(bh * NQB + blk) * 2 + ks) * 64 + lane] = v;
        }
    } else {
        const int wid = (blockIdx.x - 2048) * 4 + wv;   // 0..2047
        const int bh  = wid >> 6;
        const int u   = wid & 63;

        const float* src = V + ((size_t)bh * S_SZ + u * 32) * D_SZ;
        float* t = vt[wv];
        #pragma unroll
        for (int i = 0; i < 8; ++i) {
            int idx = i * 64 + lane;
            int row = idx >> 4;
            int c4  = idx & 15;
            *(f32x4*)(t + row * 68 + c4 * 4) = *(const f32x4*)(src + row * 64 + c4 * 4);
        }
        __syncthreads();

        half8* vsw = (half8*)(ws + VSW_OFF);
        #pragma unroll
        for (int db = 0; db < 4; ++db) {
            half8 vb;
            #pragma unroll
            for (int j = 0; j < 8; ++j) {
                int kk = (j < 4) ? (4 * g + j) : (16 + 4 * g + (j - 4));
                vb[j] = (_Float16)t[kk * 68 + 16 * db + l15];
            }
            vsw[((size_t)(bh * NUB + u) * 4 + db) * 64 + lane] = vb;
        }
    }
}

// ---- main fused kernel (R12 skeleton; sweep moved AFTER PV).
// Order: QK^T -> softmax -> stage W in LDS -> PV (V loads precede any W
// stores in the vmem queue -> no false store-drain dependency) -> sweep
// NT burst -> barrier (vmcnt drain covered by co-resident wg) -> ctxred.
__global__ __launch_bounds__(512, 4) void attn_fused10(
    const char* __restrict__ ws, float* __restrict__ OutC, float* __restrict__ OutW)
{
    __shared__ __align__(16) char smem[66560];   // 64KB W-tile + redm + reds
    float* redm = (float*)(smem + 65536);        // [8][16]
    float* reds = (float*)(smem + 65536 + 512);  // [8][16]

    const int tid  = threadIdx.x;
    const int lane = tid & 63;
    const int wv   = tid >> 6;
    const int l15  = lane & 15;
    const int g    = lane >> 4;

    // XCD-aware swizzle: XCD x owns bh range [4x, 4x+4)
    const int b    = blockIdx.x;
    const int work = (b & 7) * 512 + (b >> 3);
    const int bh   = work >> 7;
    const int qt   = work & 127;
    const int q0   = qt * 16;

    const half8* QF  = (const half8*)(ws + QF_OFF);
    const half8* KF  = (const half8*)(ws + KF_OFF);
    const half8* VSW = (const half8*)(ws + VSW_OFF);

    float* Wb = OutW + (size_t)bh * S_SZ * S_SZ;
    float* Cb = OutC + (size_t)bh * S_SZ * D_SZ;

    // Q fragments
    half8 qf[2];
    {
        size_t qi = ((size_t)(bh * NQB + qt) * 2) * 64 + lane;
        qf[0] = QF[qi];       qf[1] = QF[qi + 64];
    }

    // QK^T: 16 col-blocks per wave, 2 fp16 MFMA each
    f32x4 s[16];
    const int kb0 = wv * 16;
    #pragma unroll
    for (int cb = 0; cb < 16; ++cb) {
        size_t bi = ((size_t)(bh * NQB + kb0 + cb) * 2) * 64 + lane;
        half8 kf0 = KF[bi], kf1 = KF[bi + 64];
        f32x4 acc = {0.f, 0.f, 0.f, 0.f};
        acc = __builtin_amdgcn_mfma_f32_16x16x32_f16(kf0, qf[0], acc, 0, 0, 0);
        acc = __builtin_amdgcn_mfma_f32_16x16x32_f16(kf1, qf[1], acc, 0, 0, 0);
        s[cb] = acc;
    }

    // row max
    float m = -3.0e38f;
    #pragma unroll
    for (int cb = 0; cb < 16; ++cb) {
        #pragma unroll
        for (int r = 0; r < 4; ++r) m = fmaxf(m, s[cb][r]);
    }
    m = fmaxf(m, __shfl_xor(m, 16));
    m = fmaxf(m, __shfl_xor(m, 32));
    if (lane < 16) redm[wv * 16 + l15] = m;
    __syncthreads();
    float mall = redm[l15];
    #pragma unroll
    for (int w2 = 1; w2 < WAVES; ++w2) mall = fmaxf(mall, redm[w2 * 16 + l15]);

    // exp + row sum
    float sm = 0.f;
    #pragma unroll
    for (int cb = 0; cb < 16; ++cb) {
        #pragma unroll
        for (int r = 0; r < 4; ++r) {
            float e = __expf(s[cb][r] - mall);
            s[cb][r] = e;
            sm += e;
        }
    }
    sm += __shfl_xor(sm, 16);
    sm += __shfl_xor(sm, 32);
    if (lane < 16) reds[wv * 16 + l15] = sm;
    __syncthreads();
    float lsum = 0.f;
    #pragma unroll
    for (int w2 = 0; w2 < WAVES; ++w2) lsum += reds[w2 * 16 + l15];
    const float inv = 1.0f / lsum;

    // normalize -> pack P to fp16 -> stage W tile in LDS (frees s[])
    // byte = row*4096 + ((c4*8) ^ ((row&7)<<4))
    half8 pa[8];
    const int swz = (l15 & 7) << 4;
    #pragma unroll
    for (int u = 0; u < 8; ++u) {
        f32x4 w0, w1;
        #pragma unroll
        for (int r = 0; r < 4; ++r) {
            w0[r] = s[2 * u][r]     * inv;
            w1[r] = s[2 * u + 1][r] * inv;
        }
        #pragma unroll
        for (int r = 0; r < 4; ++r) {
            pa[u][r]     = (_Float16)w0[r];
            pa[u][4 + r] = (_Float16)w1[r];
        }
        const uint2* pau = (const uint2*)&pa[u];
        int c4a = wv * 64 + (2 * u) * 4 + g;
        int c4b = c4a + 4;
        *(uint2*)(smem + l15 * 4096 + ((c4a * 8) ^ swz)) = pau[0];
        *(uint2*)(smem + l15 * 4096 + ((c4b * 8) ^ swz)) = pau[1];
    }
    __syncthreads();

    // PV FIRST: V loads enter the vmem queue before any W stores
    f32x4 ctx[4];
    #pragma unroll
    for (int db = 0; db < 4; ++db) ctx[db] = (f32x4){0.f, 0.f, 0.f, 0.f};
    #pragma unroll
    for (int u = 0; u < 8; ++u) {
        size_t vbase = ((size_t)(bh * NUB + wv * 8 + u) * 4) * 64 + lane;
        #pragma unroll
        for (int db = 0; db < 4; ++db) {
            half8 vb = VSW[vbase + (size_t)db * 64];
            ctx[db] = __builtin_amdgcn_mfma_f32_16x16x32_f16(pa[u], vb, ctx[db], 0, 0, 0);
        }
    }

    // sweep-out: row-major contiguous NT burst (after PV's loads)
    {
        float* Wrow = Wb + (size_t)q0 * S_SZ;
        #pragma unroll
        for (int sidx = 0; sidx < 16; ++sidx) {
            int unit = sidx * 512 + tid;           // 8B units; 512 units/row
            int row  = unit >> 9;
            int c4   = unit & 511;
            half4 hv = *(const half4*)(smem + row * 4096 + ((c4 * 8) ^ ((row & 7) << 4)));
            f32x4 f;
            #pragma unroll
            for (int j = 0; j < 4; ++j) f[j] = (float)hv[j];
            __builtin_nontemporal_store(f, (f32x4*)(Wrow + (size_t)row * S_SZ + c4 * 4));
        }
    }

    // ctxred reusing W-LDS (barrier drains stores; co-resident wg covers)
    __syncthreads();
    float* ctxred = (float*)smem;    // [8][16][64]
    #pragma unroll
    for (int db = 0; db < 4; ++db) {
        #pragma unroll
        for (int r = 0; r < 4; ++r)
            ctxred[(wv * 16 + 4 * g + r) * 64 + 16 * db + l15] = ctx[db][r];
    }
    __syncthreads();
    {
        const int qr = tid >> 6;
        const int d  = tid & 63;
        float acc0 = 0.f, acc1 = 0.f;
        #pragma unroll
        for (int w2 = 0; w2 < WAVES; ++w2) {
            acc0 += ctxred[(w2 * 16 + qr) * 64 + d];
            acc1 += ctxred[(w2 * 16 + qr + 8) * 64 + d];
        }
        __builtin_nontemporal_store(acc0, Cb + (size_t)(q0 + qr) * D_SZ + d);
        __builtin_nontemporal_store(acc1, Cb + (size_t)(q0 + qr + 8) * D_SZ + d);
    }
}

extern "C" void kernel_launch(void* const* d_in, const int* in_sizes, int n_in,
                              void* d_out, int out_size, void* d_ws, size_t ws_size,
                              hipStream_t stream)
{
    const float* Q = (const float*)d_in[0];
    const float* K = (const float*)d_in[1];
    const float* V = (const float*)d_in[2];
    float* ctx = (float*)d_out;
    float* w   = (float*)d_out + (size_t)B_SZ * H_SZ * S_SZ * D_SZ;
    char*  ws  = (char*)d_ws;

    prep_qkv<<<2560, 256, 0, stream>>>(Q, K, V, ws);
    attn_fused10<<<4096, 512, 0, stream>>>(ws, ctx, w);
}

// Round 14
// 144.111 us; speedup vs baseline: 9.8244x; 1.0332x over previous
//
#include <hip/hip_runtime.h>
#include <hip/hip_bf16.h>

#define B_SZ 2
#define H_SZ 16
#define S_SZ 2048
#define D_SZ 64
#define WAVES 8
#define NBH  (B_SZ * H_SZ)      // 32
#define NQB  (S_SZ / 16)        // 128 16-row blocks
#define NUB  (S_SZ / 32)        // 64 32-row V blocks

typedef _Float16 half8 __attribute__((ext_vector_type(8)));
typedef _Float16 half4 __attribute__((ext_vector_type(4)));
typedef float    f32x4 __attribute__((ext_vector_type(4)));

// d_ws layout: pre-swizzled fp16 MFMA fragments (8 MB segments)
#define SEG   (8u * 1024u * 1024u)
#define QF_OFF  (0 * (size_t)SEG)
#define KF_OFF  (1 * (size_t)SEG)
#define VSW_OFF (2 * (size_t)SEG)

// ---- fused prep: blocks [0,2048) convert Q/K to fp16 fragments;
// blocks [2048,2560) build pi-permuted V fragments via LDS transpose.
__global__ __launch_bounds__(256) void prep_qkv(
    const float* __restrict__ Q, const float* __restrict__ K,
    const float* __restrict__ V, char* __restrict__ ws)
{
    __shared__ float vt[4][32 * 68];
    const int lane = threadIdx.x & 63;
    const int wv   = threadIdx.x >> 6;
    const int l15  = lane & 15;
    const int g    = lane >> 4;

    if (blockIdx.x < 2048) {
        const int wid  = blockIdx.x * 4 + wv;      // 0..8191
        const int tensor = wid >> 12;
        const int rem  = wid & 4095;
        const int bh   = rem >> 7;
        const int blk  = rem & 127;

        const float* src = (tensor ? K : Q) + ((size_t)bh * S_SZ + blk * 16 + l15) * D_SZ;
        half8* dst = (half8*)(ws + (tensor ? KF_OFF : QF_OFF));

        #pragma unroll
        for (int ks = 0; ks < 2; ++ks) {
            const float* p = src + 32 * ks + 8 * g;
            f32x4 a = *(const f32x4*)p;
            f32x4 b = *(const f32x4*)(p + 4);
            half8 v;
            #pragma unroll
            for (int j = 0; j < 4; ++j) {
                v[j]     = (_Float16)a[j];
                v[4 + j] = (_Float16)b[j];
            }
            dst[((size_t)(bh * NQB + blk) * 2 + ks) * 64 + lane] = v;
        }
    } else {
        const int wid = (blockIdx.x - 2048) * 4 + wv;   // 0..2047
        const int bh  = wid >> 6;
        const int u   = wid & 63;

        const float* src = V + ((size_t)bh * S_SZ + u * 32) * D_SZ;
        float* t = vt[wv];
        #pragma unroll
        for (int i = 0; i < 8; ++i) {
            int idx = i * 64 + lane;
            int row = idx >> 4;
            int c4  = idx & 15;
            *(f32x4*)(t + row * 68 + c4 * 4) = *(const f32x4*)(src + row * 64 + c4 * 4);
        }
        __syncthreads();

        half8* vsw = (half8*)(ws + VSW_OFF);
        #pragma unroll
        for (int db = 0; db < 4; ++db) {
            half8 vb;
            #pragma unroll
            for (int j = 0; j < 8; ++j) {
                int kk = (j < 4) ? (4 * g + j) : (16 + 4 * g + (j - 4));
                vb[j] = (_Float16)t[kk * 68 + 16 * db + l15];
            }
            vsw[((size_t)(bh * NUB + u) * 4 + db) * 64 + lane] = vb;
        }
    }
}

// ---- main fused kernel (R13 skeleton + parity-alternated PV/sweep order).
// Even wgs: PV -> sweep. Odd wgs: sweep -> PV. Co-resident wgs on a CU sit
// in opposite phases, so W-store drain (HBM pipe) runs concurrently with
// V-fragment reads (L2 pipe) chip-wide instead of alternating.
__global__ __launch_bounds__(512, 4) void attn_fused11(
    const char* __restrict__ ws, float* __restrict__ OutC, float* __restrict__ OutW)
{
    __shared__ __align__(16) char smem[66560];   // 64KB W-tile + redm + reds
    float* redm = (float*)(smem + 65536);        // [8][16]
    float* reds = (float*)(smem + 65536 + 512);  // [8][16]

    const int tid  = threadIdx.x;
    const int lane = tid & 63;
    const int wv   = tid >> 6;
    const int l15  = lane & 15;
    const int g    = lane >> 4;

    // XCD-aware swizzle: XCD x owns bh range [4x, 4x+4)
    const int b    = blockIdx.x;
    const int work = (b & 7) * 512 + (b >> 3);
    const int bh   = work >> 7;
    const int qt   = work & 127;
    const int q0   = qt * 16;

    const half8* QF  = (const half8*)(ws + QF_OFF);
    const half8* KF  = (const half8*)(ws + KF_OFF);
    const half8* VSW = (const half8*)(ws + VSW_OFF);

    float* Wb = OutW + (size_t)bh * S_SZ * S_SZ;
    float* Cb = OutC + (size_t)bh * S_SZ * D_SZ;

    // Q fragments
    half8 qf[2];
    {
        size_t qi = ((size_t)(bh * NQB + qt) * 2) * 64 + lane;
        qf[0] = QF[qi];       qf[1] = QF[qi + 64];
    }

    // QK^T: 16 col-blocks per wave, 2 fp16 MFMA each
    f32x4 s[16];
    const int kb0 = wv * 16;
    #pragma unroll
    for (int cb = 0; cb < 16; ++cb) {
        size_t bi = ((size_t)(bh * NQB + kb0 + cb) * 2) * 64 + lane;
        half8 kf0 = KF[bi], kf1 = KF[bi + 64];
        f32x4 acc = {0.f, 0.f, 0.f, 0.f};
        acc = __builtin_amdgcn_mfma_f32_16x16x32_f16(kf0, qf[0], acc, 0, 0, 0);
        acc = __builtin_amdgcn_mfma_f32_16x16x32_f16(kf1, qf[1], acc, 0, 0, 0);
        s[cb] = acc;
    }

    // row max
    float m = -3.0e38f;
    #pragma unroll
    for (int cb = 0; cb < 16; ++cb) {
        #pragma unroll
        for (int r = 0; r < 4; ++r) m = fmaxf(m, s[cb][r]);
    }
    m = fmaxf(m, __shfl_xor(m, 16));
    m = fmaxf(m, __shfl_xor(m, 32));
    if (lane < 16) redm[wv * 16 + l15] = m;
    __syncthreads();
    float mall = redm[l15];
    #pragma unroll
    for (int w2 = 1; w2 < WAVES; ++w2) mall = fmaxf(mall, redm[w2 * 16 + l15]);

    // exp + row sum
    float sm = 0.f;
    #pragma unroll
    for (int cb = 0; cb < 16; ++cb) {
        #pragma unroll
        for (int r = 0; r < 4; ++r) {
            float e = __expf(s[cb][r] - mall);
            s[cb][r] = e;
            sm += e;
        }
    }
    sm += __shfl_xor(sm, 16);
    sm += __shfl_xor(sm, 32);
    if (lane < 16) reds[wv * 16 + l15] = sm;
    __syncthreads();
    float lsum = 0.f;
    #pragma unroll
    for (int w2 = 0; w2 < WAVES; ++w2) lsum += reds[w2 * 16 + l15];
    const float inv = 1.0f / lsum;

    // normalize -> pack P to fp16 -> stage W tile in LDS (frees s[])
    half8 pa[8];
    const int swz = (l15 & 7) << 4;
    #pragma unroll
    for (int u = 0; u < 8; ++u) {
        f32x4 w0, w1;
        #pragma unroll
        for (int r = 0; r < 4; ++r) {
            w0[r] = s[2 * u][r]     * inv;
            w1[r] = s[2 * u + 1][r] * inv;
        }
        #pragma unroll
        for (int r = 0; r < 4; ++r) {
            pa[u][r]     = (_Float16)w0[r];
            pa[u][4 + r] = (_Float16)w1[r];
        }
        const uint2* pau = (const uint2*)&pa[u];
        int c4a = wv * 64 + (2 * u) * 4 + g;
        int c4b = c4a + 4;
        *(uint2*)(smem + l15 * 4096 + ((c4a * 8) ^ swz)) = pau[0];
        *(uint2*)(smem + l15 * 4096 + ((c4b * 8) ^ swz)) = pau[1];
    }
    __syncthreads();

    f32x4 ctx[4];
    #pragma unroll
    for (int db = 0; db < 4; ++db) ctx[db] = (f32x4){0.f, 0.f, 0.f, 0.f};

    const bool pvFirst = (work & 1) == 0;

    if (pvFirst) {
        // PV then sweep
        #pragma unroll
        for (int u = 0; u < 8; ++u) {
            size_t vbase = ((size_t)(bh * NUB + wv * 8 + u) * 4) * 64 + lane;
            #pragma unroll
            for (int db = 0; db < 4; ++db) {
                half8 vb = VSW[vbase + (size_t)db * 64];
                ctx[db] = __builtin_amdgcn_mfma_f32_16x16x32_f16(pa[u], vb, ctx[db], 0, 0, 0);
            }
        }
        float* Wrow = Wb + (size_t)q0 * S_SZ;
        #pragma unroll
        for (int sidx = 0; sidx < 16; ++sidx) {
            int unit = sidx * 512 + tid;
            int row  = unit >> 9;
            int c4   = unit & 511;
            half4 hv = *(const half4*)(smem + row * 4096 + ((c4 * 8) ^ ((row & 7) << 4)));
            f32x4 f;
            #pragma unroll
            for (int j = 0; j < 4; ++j) f[j] = (float)hv[j];
            __builtin_nontemporal_store(f, (f32x4*)(Wrow + (size_t)row * S_SZ + c4 * 4));
        }
    } else {
        // sweep then PV
        float* Wrow = Wb + (size_t)q0 * S_SZ;
        #pragma unroll
        for (int sidx = 0; sidx < 16; ++sidx) {
            int unit = sidx * 512 + tid;
            int row  = unit >> 9;
            int c4   = unit & 511;
            half4 hv = *(const half4*)(smem + row * 4096 + ((c4 * 8) ^ ((row & 7) << 4)));
            f32x4 f;
            #pragma unroll
            for (int j = 0; j < 4; ++j) f[j] = (float)hv[j];
            __builtin_nontemporal_store(f, (f32x4*)(Wrow + (size_t)row * S_SZ + c4 * 4));
        }
        #pragma unroll
        for (int u = 0; u < 8; ++u) {
            size_t vbase = ((size_t)(bh * NUB + wv * 8 + u) * 4) * 64 + lane;
            #pragma unroll
            for (int db = 0; db < 4; ++db) {
                half8 vb = VSW[vbase + (size_t)db * 64];
                ctx[db] = __builtin_amdgcn_mfma_f32_16x16x32_f16(pa[u], vb, ctx[db], 0, 0, 0);
            }
        }
    }

    // ctxred reusing W-LDS
    __syncthreads();
    float* ctxred = (float*)smem;    // [8][16][64]
    #pragma unroll
    for (int db = 0; db < 4; ++db) {
        #pragma unroll
        for (int r = 0; r < 4; ++r)
            ctxred[(wv * 16 + 4 * g + r) * 64 + 16 * db + l15] = ctx[db][r];
    }
    __syncthreads();
    {
        const int qr = tid >> 6;
        const int d  = tid & 63;
        float acc0 = 0.f, acc1 = 0.f;
        #pragma unroll
        for (int w2 = 0; w2 < WAVES; ++w2) {
            acc0 += ctxred[(w2 * 16 + qr) * 64 + d];
            acc1 += ctxred[(w2 * 16 + qr + 8) * 64 + d];
        }
        __builtin_nontemporal_store(acc0, Cb + (size_t)(q0 + qr) * D_SZ + d);
        __builtin_nontemporal_store(acc1, Cb + (size_t)(q0 + qr + 8) * D_SZ + d);
    }
}

extern "C" void kernel_launch(void* const* d_in, const int* in_sizes, int n_in,
                              void* d_out, int out_size, void* d_ws, size_t ws_size,
                              hipStream_t stream)
{
    const float* Q = (const float*)d_in[0];
    const float* K = (const float*)d_in[1];
    const float* V = (const float*)d_in[2];
    float* ctx = (float*)d_out;
    float* w   = (float*)d_out + (size_t)B_SZ * H_SZ * S_SZ * D_SZ;
    char*  ws  = (char*)d_ws;

    prep_qkv<<<2560, 256, 0, stream>>>(Q, K, V, ws);
    attn_fused11<<<4096, 512, 0, stream>>>(ws, ctx, w);
}